// Round 16
// baseline (891.948 us; speedup 1.0000x reference)
//
#include <hip/hip_runtime.h>

#define IN_DIM 128
#define HID    64
#define OUTD   32

#define BSHIFT 9
#define BNODES 512                 // 1 << BSHIFT
#define NB     196                 // ceil(100000 / 512)
#define BCAP   16384               // capped bucket slots (mean occupancy ~8163)
#define CHUNK  4096                // edges per k_bscatter block (E % 4 == 0 assumed)

#define XPAD   136                 // bf16 row pad

typedef __attribute__((ext_vector_type(8))) short bf16x8;
typedef __attribute__((ext_vector_type(4))) float f32x4;

// ---- bf16 helpers ----

__device__ __forceinline__ unsigned bfp2(float x, float y) {
    unsigned a = __float_as_uint(x); a = a + 0x7FFF + ((a >> 16) & 1);
    unsigned b = __float_as_uint(y); b = b + 0x7FFF + ((b >> 16) & 1);
    return (a >> 16) | (b & 0xFFFF0000u);
}

__device__ __forceinline__ unsigned short bf1(float x) {
    unsigned u = __float_as_uint(x);
    u += 0x7FFF + ((u >> 16) & 1);
    return (unsigned short)(u >> 16);
}

// store 8 bf16 (from uint4) as f32 into LDS row
__device__ __forceinline__ void store8(float* a, uint4 q) {
    a[0] = __uint_as_float(q.x << 16); a[1] = __uint_as_float(q.x & 0xFFFF0000u);
    a[2] = __uint_as_float(q.y << 16); a[3] = __uint_as_float(q.y & 0xFFFF0000u);
    a[4] = __uint_as_float(q.z << 16); a[5] = __uint_as_float(q.z & 0xFFFF0000u);
    a[6] = __uint_as_float(q.w << 16); a[7] = __uint_as_float(q.w & 0xFFFF0000u);
}

// atomically add 8 bf16 (from uint4) into LDS row (ds_add_f32)
__device__ __forceinline__ void atomAdd8(float* a, uint4 q) {
    atomicAdd(a + 0, __uint_as_float(q.x << 16));
    atomicAdd(a + 1, __uint_as_float(q.x & 0xFFFF0000u));
    atomicAdd(a + 2, __uint_as_float(q.y << 16));
    atomicAdd(a + 3, __uint_as_float(q.y & 0xFFFF0000u));
    atomicAdd(a + 4, __uint_as_float(q.z << 16));
    atomicAdd(a + 5, __uint_as_float(q.z & 0xFFFF0000u));
    atomicAdd(a + 6, __uint_as_float(q.w << 16));
    atomicAdd(a + 7, __uint_as_float(q.w & 0xFFFF0000u));
}

// ================= init bucket cursors =================

__global__ void k_binit(int* __restrict__ bucketCursor) {
    int t = threadIdx.x;
    if (t < NB) bucketCursor[t] = t * BCAP;
}

// ================= single-pass bucket scatter (packed src<<9 | dst_local) =================

__launch_bounds__(256)
__global__ void k_bscatter(const int* __restrict__ src, const int* __restrict__ dst,
                           int* __restrict__ bucketCursor, int* __restrict__ ebuf, int E) {
    __shared__ int h[NB];
    __shared__ int lbase[NB];
    __shared__ int lcur[NB];
    const int t = threadIdx.x;
    const int base = blockIdx.x * CHUNK;
    const int nI4 = (min(CHUNK, E - base)) >> 2;
    const int4* d4 = (const int4*)(dst + base);
    const int4* s4 = (const int4*)(src + base);

    int4 dv0, dv1, dv2, dv3;
    const bool v0 = t < nI4, v1 = t + 256 < nI4, v2 = t + 512 < nI4, v3 = t + 768 < nI4;
    if (v0) dv0 = d4[t];
    if (v1) dv1 = d4[t + 256];
    if (v2) dv2 = d4[t + 512];
    if (v3) dv3 = d4[t + 768];

    for (int i = t; i < NB; i += 256) { h[i] = 0; lcur[i] = 0; }
    __syncthreads();

    if (v0) { atomicAdd(&h[dv0.x >> BSHIFT], 1); atomicAdd(&h[dv0.y >> BSHIFT], 1);
              atomicAdd(&h[dv0.z >> BSHIFT], 1); atomicAdd(&h[dv0.w >> BSHIFT], 1); }
    if (v1) { atomicAdd(&h[dv1.x >> BSHIFT], 1); atomicAdd(&h[dv1.y >> BSHIFT], 1);
              atomicAdd(&h[dv1.z >> BSHIFT], 1); atomicAdd(&h[dv1.w >> BSHIFT], 1); }
    if (v2) { atomicAdd(&h[dv2.x >> BSHIFT], 1); atomicAdd(&h[dv2.y >> BSHIFT], 1);
              atomicAdd(&h[dv2.z >> BSHIFT], 1); atomicAdd(&h[dv2.w >> BSHIFT], 1); }
    if (v3) { atomicAdd(&h[dv3.x >> BSHIFT], 1); atomicAdd(&h[dv3.y >> BSHIFT], 1);
              atomicAdd(&h[dv3.z >> BSHIFT], 1); atomicAdd(&h[dv3.w >> BSHIFT], 1); }
    __syncthreads();

    for (int i = t; i < NB; i += 256)
        lbase[i] = h[i] ? atomicAdd(&bucketCursor[i], h[i]) : 0;
    __syncthreads();

    #define SC1(D, S) { int b_ = (D) >> BSHIFT; int off_ = atomicAdd(&lcur[b_], 1); \
                        ebuf[lbase[b_] + off_] = ((S) << BSHIFT) | ((D) & (BNODES - 1)); }
    if (v0) { int4 sv = s4[t];       SC1(dv0.x, sv.x); SC1(dv0.y, sv.y); SC1(dv0.z, sv.z); SC1(dv0.w, sv.w); }
    if (v1) { int4 sv = s4[t + 256]; SC1(dv1.x, sv.x); SC1(dv1.y, sv.y); SC1(dv1.z, sv.z); SC1(dv1.w, sv.w); }
    if (v2) { int4 sv = s4[t + 512]; SC1(dv2.x, sv.x); SC1(dv2.y, sv.y); SC1(dv2.z, sv.z); SC1(dv2.w, sv.w); }
    if (v3) { int4 sv = s4[t + 768]; SC1(dv3.x, sv.x); SC1(dv3.y, sv.y); SC1(dv3.z, sv.z); SC1(dv3.w, sv.w); }
    #undef SC1
}

// ================= per-bucket fine CSR build (PACKED words) + rs/re + dinv =================

__launch_bounds__(256)
__global__ void k_bfinal(const int* __restrict__ ebuf, const int* __restrict__ bucketCursor,
                         int* __restrict__ rs, int* __restrict__ re, float* __restrict__ dinv,
                         int* __restrict__ csr, int N) {
    __shared__ int hist[BNODES];
    __shared__ int rsl[BNODES];
    __shared__ int ssum[256];
    const int t = threadIdx.x;
    const int b = blockIdx.x;
    const int nodeBase = b << BSHIFT;
    const int ebase = b * BCAP;
    const int cnt = bucketCursor[b] - ebase;
    const int nI4 = cnt >> 2;
    const int4* e4 = (const int4*)(ebuf + ebase);

    hist[t] = 0; hist[t + 256] = 0;
    __syncthreads();
    for (int i = t; i < nI4; i += 256) {
        int4 v = e4[i];
        atomicAdd(&hist[v.x & (BNODES - 1)], 1);
        atomicAdd(&hist[v.y & (BNODES - 1)], 1);
        atomicAdd(&hist[v.z & (BNODES - 1)], 1);
        atomicAdd(&hist[v.w & (BNODES - 1)], 1);
    }
    if (t < (cnt & 3))
        atomicAdd(&hist[ebuf[ebase + (nI4 << 2) + t] & (BNODES - 1)], 1);
    __syncthreads();

    int h0 = hist[2 * t], h1 = hist[2 * t + 1];
    ssum[t] = h0 + h1;
    __syncthreads();
    for (int off = 1; off < 256; off <<= 1) {
        int u = (t >= off) ? ssum[t - off] : 0;
        __syncthreads();
        ssum[t] += u;
        __syncthreads();
    }
    int excl = ssum[t] - h0 - h1;
    rsl[2 * t]     = excl;
    rsl[2 * t + 1] = excl + h0;

    int n0 = nodeBase + 2 * t, n1 = n0 + 1;
    if (n0 < N) {
        rs[n0] = ebase + excl;           re[n0] = ebase + excl + h0;
        dinv[n0] = rsqrtf((float)h0 + 1.0f);
    }
    if (n1 < N) {
        rs[n1] = ebase + excl + h0;      re[n1] = ebase + excl + h0 + h1;
        dinv[n1] = rsqrtf((float)h1 + 1.0f);
    }

    hist[2 * t] = 0; hist[2 * t + 1] = 0;   // reuse as per-node cursors
    __syncthreads();

    #define FILL1(P) { int l_ = (P) & (BNODES - 1); int off_ = atomicAdd(&hist[l_], 1); \
                       csr[ebase + rsl[l_] + off_] = (P); }
    for (int i = t; i < nI4; i += 256) {
        int4 v = e4[i];
        FILL1(v.x); FILL1(v.y); FILL1(v.z); FILL1(v.w);
    }
    if (t < (cnt & 3))
        FILL1(ebuf[ebase + (nI4 << 2) + t]);
    #undef FILL1
}

// ================= layer 1 GEMM via MFMA: hs1 (bf16 [N][64]) = (x @ W1) * dinv[row] =================

__launch_bounds__(256)
__global__ void k_gemm1(const float* __restrict__ x, const float* __restrict__ W1,
                        const float* __restrict__ dinv, unsigned short* __restrict__ hs1b, int N) {
    __shared__ unsigned short xsb[64 * XPAD];
    __shared__ unsigned short wsb[64 * XPAD];
    const int t = threadIdx.x;
    const int base = blockIdx.x * 64;

    for (int i = t; i < IN_DIM * HID; i += 256) {
        int k = i >> 6, n = i & 63;
        wsb[n * XPAD + k] = bf1(W1[i]);
    }
    {
        const float4* s4 = (const float4*)(x + (size_t)base * IN_DIM);
        #pragma unroll
        for (int j = 0; j < 8; ++j) {
            int idx = t + j * 256;
            int r = idx >> 5, k4 = (idx & 31) * 4;
            ushort4 o;
            if (base + r < N) {
                float4 v = s4[idx];
                o.x = bf1(v.x); o.y = bf1(v.y); o.z = bf1(v.z); o.w = bf1(v.w);
            } else {
                o.x = 0; o.y = 0; o.z = 0; o.w = 0;
            }
            *(ushort4*)&xsb[r * XPAD + k4] = o;
        }
    }
    __syncthreads();

    const int lane = t & 63;
    const int w    = t >> 6;
    const int lr   = lane & 15;
    const int kg   = lane >> 4;

    f32x4 acc0 = {0,0,0,0}, acc1 = {0,0,0,0}, acc2 = {0,0,0,0}, acc3 = {0,0,0,0};
    #pragma unroll
    for (int kb = 0; kb < 4; ++kb) {
        int ko = kb * 32 + kg * 8;
        bf16x8 af = *(const bf16x8*)&xsb[(w * 16 + lr) * XPAD + ko];
        bf16x8 b0 = *(const bf16x8*)&wsb[( 0 + lr) * XPAD + ko];
        bf16x8 b1 = *(const bf16x8*)&wsb[(16 + lr) * XPAD + ko];
        bf16x8 b2 = *(const bf16x8*)&wsb[(32 + lr) * XPAD + ko];
        bf16x8 b3 = *(const bf16x8*)&wsb[(48 + lr) * XPAD + ko];
        acc0 = __builtin_amdgcn_mfma_f32_16x16x32_bf16(af, b0, acc0, 0, 0, 0);
        acc1 = __builtin_amdgcn_mfma_f32_16x16x32_bf16(af, b1, acc1, 0, 0, 0);
        acc2 = __builtin_amdgcn_mfma_f32_16x16x32_bf16(af, b2, acc2, 0, 0, 0);
        acc3 = __builtin_amdgcn_mfma_f32_16x16x32_bf16(af, b3, acc3, 0, 0, 0);
    }

    #pragma unroll
    for (int j = 0; j < 4; ++j) {
        int node = base + w * 16 + kg * 4 + j;
        if (node < N) {
            float d = dinv[node];
            unsigned short* o = hs1b + (size_t)node * HID + lr;
            o[0]  = bf1(acc0[j] * d);
            o[16] = bf1(acc1[j] * d);
            o[32] = bf1(acc2[j] * d);
            o[48] = bf1(acc3[j] * d);
        }
    }
}

// ================= FUSED: EDGE-PARALLEL agg1 (LDS f32 atomics) + relu/bias + layer-2 GEMM =================
// 256 threads, 32 nodes/block. Block's csr range [rs[base], re[base+31]) is CONTIGUOUS
// (bucketed CSR, 32 | 512). Edge-parallel gather = perfect load balance across degrees.

__launch_bounds__(256)
__global__ void k_fuse2(const uint4* __restrict__ hs, const int* __restrict__ rs,
                        const int* __restrict__ re, const int* __restrict__ csr,
                        const float* __restrict__ dinv,
                        const float* __restrict__ b1, const float* __restrict__ W2,
                        uint2* __restrict__ hs2b, int N) {
    __shared__ float Ws[HID * OUTD];   // 8 KB [k][f]
    __shared__ float L1s[32 * 68];     // accumulators, pad 68 (bank spread 4*li+8*lane+j)
    const int t = threadIdx.x;
    const int base = blockIdx.x * 32;
    const int nl = t >> 3;      // node-local / edge-group 0..31
    const int lane = t & 7;     // 16B sub-row

    for (int i = t; i < HID * OUTD / 4; i += 256)
        ((float4*)Ws)[i] = ((const float4*)W2)[i];

    // init acc with self-loop row
    store8(&L1s[nl * 68 + lane * 8], hs[(size_t)(base + nl) * 8 + lane]);
    __syncthreads();

    {   // edge-parallel gather, 2-deep
        const int rs0 = rs[base];
        const int reL = re[base + 31];
        const int firstLocal = base & (BNODES - 1);
        int e = rs0 + nl;
        while (e + 32 < reL) {
            int p0 = csr[e];
            int p1 = csr[e + 32];
            uint4 q0 = hs[(size_t)(((unsigned)p0) >> BSHIFT) * 8 + lane];
            uint4 q1 = hs[(size_t)(((unsigned)p1) >> BSHIFT) * 8 + lane];
            int li0 = (p0 & (BNODES - 1)) - firstLocal;
            int li1 = (p1 & (BNODES - 1)) - firstLocal;
            atomAdd8(&L1s[li0 * 68 + lane * 8], q0);
            atomAdd8(&L1s[li1 * 68 + lane * 8], q1);
            e += 64;
        }
        if (e < reL) {
            int p0 = csr[e];
            uint4 q0 = hs[(size_t)(((unsigned)p0) >> BSHIFT) * 8 + lane];
            int li0 = (p0 & (BNODES - 1)) - firstLocal;
            atomAdd8(&L1s[li0 * 68 + lane * 8], q0);
        }
    }
    __syncthreads();

    {   // epilogue: L1 = relu(dinv*acc + b1) in place
        float dn = dinv[base + nl];
        const float4* bb4 = (const float4*)(b1 + lane * 8);
        float4 bv0 = bb4[0], bv1 = bb4[1];
        float* a = &L1s[nl * 68 + lane * 8];
        a[0] = fmaxf(a[0] * dn + bv0.x, 0.0f);
        a[1] = fmaxf(a[1] * dn + bv0.y, 0.0f);
        a[2] = fmaxf(a[2] * dn + bv0.z, 0.0f);
        a[3] = fmaxf(a[3] * dn + bv0.w, 0.0f);
        a[4] = fmaxf(a[4] * dn + bv1.x, 0.0f);
        a[5] = fmaxf(a[5] * dn + bv1.y, 0.0f);
        a[6] = fmaxf(a[6] * dn + bv1.z, 0.0f);
        a[7] = fmaxf(a[7] * dn + bv1.w, 0.0f);
    }
    __syncthreads();

    {   // phase 2: hs2 = (L1 @ W2) * dinv
        const int fq = t & 7;
        const int nn = t >> 3;
        float4 a = {0,0,0,0};
        #pragma unroll 8
        for (int k = 0; k < HID; ++k) {
            float4 w = ((const float4*)Ws)[k * 8 + fq];
            float xv = L1s[nn * 68 + k];
            a.x += xv * w.x; a.y += xv * w.y; a.z += xv * w.z; a.w += xv * w.w;
        }
        int n = base + nn;
        float d = dinv[n];
        a.x *= d; a.y *= d; a.z *= d; a.w *= d;
        hs2b[(size_t)n * 8 + fq] = make_uint2(bfp2(a.x, a.y), bfp2(a.z, a.w));
    }
}

// ================= EDGE-PARALLEL agg2 (LDS f32 atomics) + fused epilogue =================
// 256 threads, 32 nodes/block; 4 lanes/edge (row = 64B); acc [32][36] pad.

__launch_bounds__(256)
__global__ void k_agg2(const uint4* __restrict__ hs, const int* __restrict__ rs,
                       const int* __restrict__ re, const int* __restrict__ csr,
                       const float* __restrict__ dinv,
                       const float* __restrict__ b2, float* __restrict__ out, int N) {
    __shared__ float acc[32 * 36];
    const int t = threadIdx.x;
    const int base = blockIdx.x * 32;

    // init with self-loop (threads 0..127)
    if (t < 128) {
        int nl = t >> 2, lane = t & 3;
        store8(&acc[nl * 36 + lane * 8], hs[(size_t)(base + nl) * 4 + lane]);
    }
    __syncthreads();

    {   // edge-parallel gather: 64 groups x 4 lanes, 2-deep
        const int g = t >> 2;
        const int lane = t & 3;
        const int rs0 = rs[base];
        const int reL = re[base + 31];
        const int firstLocal = base & (BNODES - 1);
        int e = rs0 + g;
        while (e + 64 < reL) {
            int p0 = csr[e];
            int p1 = csr[e + 64];
            uint4 q0 = hs[(size_t)(((unsigned)p0) >> BSHIFT) * 4 + lane];
            uint4 q1 = hs[(size_t)(((unsigned)p1) >> BSHIFT) * 4 + lane];
            int li0 = (p0 & (BNODES - 1)) - firstLocal;
            int li1 = (p1 & (BNODES - 1)) - firstLocal;
            atomAdd8(&acc[li0 * 36 + lane * 8], q0);
            atomAdd8(&acc[li1 * 36 + lane * 8], q1);
            e += 128;
        }
        if (e < reL) {
            int p0 = csr[e];
            uint4 q0 = hs[(size_t)(((unsigned)p0) >> BSHIFT) * 4 + lane];
            int li0 = (p0 & (BNODES - 1)) - firstLocal;
            atomAdd8(&acc[li0 * 36 + lane * 8], q0);
        }
    }
    __syncthreads();

    // epilogue: out = relu(dinv*acc + b2), threads 0..127
    if (t < 128) {
        int nl = t >> 2, lane = t & 3;
        int node = base + nl;
        float dn = dinv[node];
        const float* a = &acc[nl * 36 + lane * 8];
        const float4* bb4 = (const float4*)(b2 + lane * 8);
        float4 b0 = bb4[0], b1v = bb4[1];
        float4 o0, o1;
        o0.x = fmaxf(a[0] * dn + b0.x, 0.0f);
        o0.y = fmaxf(a[1] * dn + b0.y, 0.0f);
        o0.z = fmaxf(a[2] * dn + b0.z, 0.0f);
        o0.w = fmaxf(a[3] * dn + b0.w, 0.0f);
        o1.x = fmaxf(a[4] * dn + b1v.x, 0.0f);
        o1.y = fmaxf(a[5] * dn + b1v.y, 0.0f);
        o1.z = fmaxf(a[6] * dn + b1v.z, 0.0f);
        o1.w = fmaxf(a[7] * dn + b1v.w, 0.0f);
        float4* o = (float4*)(out + (size_t)node * OUTD + lane * 8);
        o[0] = o0;
        o[1] = o1;
    }
}

// ================= launch =================

extern "C" void kernel_launch(void* const* d_in, const int* in_sizes, int n_in,
                              void* d_out, int out_size, void* d_ws, size_t ws_size,
                              hipStream_t stream) {
    const float* x  = (const float*)d_in[0];
    const int*   ei = (const int*)  d_in[1];
    const float* W1 = (const float*)d_in[2];
    const float* b1 = (const float*)d_in[3];
    const float* W2 = (const float*)d_in[4];
    const float* b2 = (const float*)d_in[5];

    const int N = in_sizes[0] / IN_DIM;   // 100000
    const int E = in_sizes[1] / 2;        // 1600000
    const int* srcI = ei;
    const int* dstI = ei + E;
    float* out = (float*)d_out;

    // workspace layout
    float* dinv         = (float*)d_ws;                       // slot 0 (131072)
    int*   rs           = (int*)d_ws + 131072;                // slot 1: N
    int*   re           = (int*)d_ws + 2 * 131072;            // slot 2: N
    int*   bucketCursor = (int*)d_ws + 3 * 131072;            // slot 3: NB
    int*   ebuf         = (int*)d_ws + 4 * 131072;            // NB*BCAP capped buckets
    int*   csr          = ebuf + (size_t)NB * BCAP;           // NB*BCAP capped CSR (packed words)
    uint2* hs1b         = (uint2*)(csr + (size_t)NB * BCAP);  // bf16 [N][64] (N*16 uint2)
    uint2* hs2b         = hs1b + (size_t)N * 16;              // bf16 [N][32] (N*8 uint2)

    k_binit   <<<1, 256, 0, stream>>>(bucketCursor);
    k_bscatter<<<(E + CHUNK - 1) / CHUNK, 256, 0, stream>>>(srcI, dstI, bucketCursor, ebuf, E);
    k_bfinal  <<<NB, 256, 0, stream>>>(ebuf, bucketCursor, rs, re, dinv, csr, N);

    k_gemm1<<<(N + 63) / 64, 256, 0, stream>>>(x, W1, dinv, (unsigned short*)hs1b, N);
    k_fuse2<<<(N + 31) / 32, 256, 0, stream>>>((const uint4*)hs1b, rs, re, csr, dinv, b1, W2, hs2b, N);
    k_agg2 <<<(N + 31) / 32, 256, 0, stream>>>((const uint4*)hs2b, rs, re, csr, dinv, b2, out, N);
}

// Round 17
// 131.576 us; speedup vs baseline: 6.7790x; 6.7790x over previous
//
#include <hip/hip_runtime.h>

#define IN_DIM 128
#define HID    64
#define OUTD   32

#define BSHIFT 9
#define BNODES 512                 // 1 << BSHIFT
#define NB     196                 // ceil(100000 / 512)
#define BCAP   16384               // capped bucket slots (mean occupancy ~8163)
#define CHUNK  4096                // edges per k_bscatter block (E % 4 == 0 assumed)

#define XPAD   136                 // bf16 row pad

typedef __attribute__((ext_vector_type(8))) short bf16x8;
typedef __attribute__((ext_vector_type(4))) float f32x4;

// ---- bf16 helpers ----

__device__ __forceinline__ unsigned bfp2(float x, float y) {
    unsigned a = __float_as_uint(x); a = a + 0x7FFF + ((a >> 16) & 1);
    unsigned b = __float_as_uint(y); b = b + 0x7FFF + ((b >> 16) & 1);
    return (a >> 16) | (b & 0xFFFF0000u);
}

__device__ __forceinline__ unsigned short bf1(float x) {
    unsigned u = __float_as_uint(x);
    u += 0x7FFF + ((u >> 16) & 1);
    return (unsigned short)(u >> 16);
}

__device__ __forceinline__ void acc8(float* f, uint4 q) {
    f[0] += __uint_as_float(q.x << 16); f[1] += __uint_as_float(q.x & 0xFFFF0000u);
    f[2] += __uint_as_float(q.y << 16); f[3] += __uint_as_float(q.y & 0xFFFF0000u);
    f[4] += __uint_as_float(q.z << 16); f[5] += __uint_as_float(q.z & 0xFFFF0000u);
    f[6] += __uint_as_float(q.w << 16); f[7] += __uint_as_float(q.w & 0xFFFF0000u);
}

// ================= init bucket cursors =================

__global__ void k_binit(int* __restrict__ bucketCursor) {
    int t = threadIdx.x;
    if (t < NB) bucketCursor[t] = t * BCAP;
}

// ================= single-pass bucket scatter (packed src<<9 | dst_local) =================

__launch_bounds__(256)
__global__ void k_bscatter(const int* __restrict__ src, const int* __restrict__ dst,
                           int* __restrict__ bucketCursor, int* __restrict__ ebuf, int E) {
    __shared__ int h[NB];
    __shared__ int lbase[NB];
    __shared__ int lcur[NB];
    const int t = threadIdx.x;
    const int base = blockIdx.x * CHUNK;
    const int nI4 = (min(CHUNK, E - base)) >> 2;
    const int4* d4 = (const int4*)(dst + base);
    const int4* s4 = (const int4*)(src + base);

    int4 dv0, dv1, dv2, dv3;
    const bool v0 = t < nI4, v1 = t + 256 < nI4, v2 = t + 512 < nI4, v3 = t + 768 < nI4;
    if (v0) dv0 = d4[t];
    if (v1) dv1 = d4[t + 256];
    if (v2) dv2 = d4[t + 512];
    if (v3) dv3 = d4[t + 768];

    for (int i = t; i < NB; i += 256) { h[i] = 0; lcur[i] = 0; }
    __syncthreads();

    if (v0) { atomicAdd(&h[dv0.x >> BSHIFT], 1); atomicAdd(&h[dv0.y >> BSHIFT], 1);
              atomicAdd(&h[dv0.z >> BSHIFT], 1); atomicAdd(&h[dv0.w >> BSHIFT], 1); }
    if (v1) { atomicAdd(&h[dv1.x >> BSHIFT], 1); atomicAdd(&h[dv1.y >> BSHIFT], 1);
              atomicAdd(&h[dv1.z >> BSHIFT], 1); atomicAdd(&h[dv1.w >> BSHIFT], 1); }
    if (v2) { atomicAdd(&h[dv2.x >> BSHIFT], 1); atomicAdd(&h[dv2.y >> BSHIFT], 1);
              atomicAdd(&h[dv2.z >> BSHIFT], 1); atomicAdd(&h[dv2.w >> BSHIFT], 1); }
    if (v3) { atomicAdd(&h[dv3.x >> BSHIFT], 1); atomicAdd(&h[dv3.y >> BSHIFT], 1);
              atomicAdd(&h[dv3.z >> BSHIFT], 1); atomicAdd(&h[dv3.w >> BSHIFT], 1); }
    __syncthreads();

    for (int i = t; i < NB; i += 256)
        lbase[i] = h[i] ? atomicAdd(&bucketCursor[i], h[i]) : 0;
    __syncthreads();

    #define SC1(D, S) { int b_ = (D) >> BSHIFT; int off_ = atomicAdd(&lcur[b_], 1); \
                        ebuf[lbase[b_] + off_] = ((S) << BSHIFT) | ((D) & (BNODES - 1)); }
    if (v0) { int4 sv = s4[t];       SC1(dv0.x, sv.x); SC1(dv0.y, sv.y); SC1(dv0.z, sv.z); SC1(dv0.w, sv.w); }
    if (v1) { int4 sv = s4[t + 256]; SC1(dv1.x, sv.x); SC1(dv1.y, sv.y); SC1(dv1.z, sv.z); SC1(dv1.w, sv.w); }
    if (v2) { int4 sv = s4[t + 512]; SC1(dv2.x, sv.x); SC1(dv2.y, sv.y); SC1(dv2.z, sv.z); SC1(dv2.w, sv.w); }
    if (v3) { int4 sv = s4[t + 768]; SC1(dv3.x, sv.x); SC1(dv3.y, sv.y); SC1(dv3.z, sv.z); SC1(dv3.w, sv.w); }
    #undef SC1
}

// ================= per-bucket fine CSR build + rs/re + dinv =================

__launch_bounds__(256)
__global__ void k_bfinal(const int* __restrict__ ebuf, const int* __restrict__ bucketCursor,
                         int* __restrict__ rs, int* __restrict__ re, float* __restrict__ dinv,
                         int* __restrict__ csr, int N) {
    __shared__ int hist[BNODES];
    __shared__ int rsl[BNODES];
    __shared__ int ssum[256];
    const int t = threadIdx.x;
    const int b = blockIdx.x;
    const int nodeBase = b << BSHIFT;
    const int ebase = b * BCAP;
    const int cnt = bucketCursor[b] - ebase;
    const int nI4 = cnt >> 2;
    const int4* e4 = (const int4*)(ebuf + ebase);

    hist[t] = 0; hist[t + 256] = 0;
    __syncthreads();
    for (int i = t; i < nI4; i += 256) {
        int4 v = e4[i];
        atomicAdd(&hist[v.x & (BNODES - 1)], 1);
        atomicAdd(&hist[v.y & (BNODES - 1)], 1);
        atomicAdd(&hist[v.z & (BNODES - 1)], 1);
        atomicAdd(&hist[v.w & (BNODES - 1)], 1);
    }
    if (t < (cnt & 3))
        atomicAdd(&hist[ebuf[ebase + (nI4 << 2) + t] & (BNODES - 1)], 1);
    __syncthreads();

    int h0 = hist[2 * t], h1 = hist[2 * t + 1];
    ssum[t] = h0 + h1;
    __syncthreads();
    for (int off = 1; off < 256; off <<= 1) {
        int u = (t >= off) ? ssum[t - off] : 0;
        __syncthreads();
        ssum[t] += u;
        __syncthreads();
    }
    int excl = ssum[t] - h0 - h1;
    rsl[2 * t]     = excl;
    rsl[2 * t + 1] = excl + h0;

    int n0 = nodeBase + 2 * t, n1 = n0 + 1;
    if (n0 < N) {
        rs[n0] = ebase + excl;           re[n0] = ebase + excl + h0;
        dinv[n0] = rsqrtf((float)h0 + 1.0f);
    }
    if (n1 < N) {
        rs[n1] = ebase + excl + h0;      re[n1] = ebase + excl + h0 + h1;
        dinv[n1] = rsqrtf((float)h1 + 1.0f);
    }

    hist[2 * t] = 0; hist[2 * t + 1] = 0;   // reuse as per-node cursors
    __syncthreads();

    #define FILL1(P) { int l_ = (P) & (BNODES - 1); int off_ = atomicAdd(&hist[l_], 1); \
                       csr[ebase + rsl[l_] + off_] = ((unsigned)(P)) >> BSHIFT; }
    for (int i = t; i < nI4; i += 256) {
        int4 v = e4[i];
        FILL1(v.x); FILL1(v.y); FILL1(v.z); FILL1(v.w);
    }
    if (t < (cnt & 3))
        FILL1(ebuf[ebase + (nI4 << 2) + t]);
    #undef FILL1
}

// ================= layer 1 GEMM via MFMA: hs1 (bf16 [N][64]) = (x @ W1) * dinv[row] =================

__launch_bounds__(256)
__global__ void k_gemm1(const float* __restrict__ x, const float* __restrict__ W1,
                        const float* __restrict__ dinv, unsigned short* __restrict__ hs1b, int N) {
    __shared__ unsigned short xsb[64 * XPAD];
    __shared__ unsigned short wsb[64 * XPAD];
    const int t = threadIdx.x;
    const int base = blockIdx.x * 64;

    for (int i = t; i < IN_DIM * HID; i += 256) {
        int k = i >> 6, n = i & 63;
        wsb[n * XPAD + k] = bf1(W1[i]);
    }
    {
        const float4* s4 = (const float4*)(x + (size_t)base * IN_DIM);
        #pragma unroll
        for (int j = 0; j < 8; ++j) {
            int idx = t + j * 256;
            int r = idx >> 5, k4 = (idx & 31) * 4;
            ushort4 o;
            if (base + r < N) {
                float4 v = s4[idx];
                o.x = bf1(v.x); o.y = bf1(v.y); o.z = bf1(v.z); o.w = bf1(v.w);
            } else {
                o.x = 0; o.y = 0; o.z = 0; o.w = 0;
            }
            *(ushort4*)&xsb[r * XPAD + k4] = o;
        }
    }
    __syncthreads();

    const int lane = t & 63;
    const int w    = t >> 6;
    const int lr   = lane & 15;
    const int kg   = lane >> 4;

    f32x4 acc0 = {0,0,0,0}, acc1 = {0,0,0,0}, acc2 = {0,0,0,0}, acc3 = {0,0,0,0};
    #pragma unroll
    for (int kb = 0; kb < 4; ++kb) {
        int ko = kb * 32 + kg * 8;
        bf16x8 af = *(const bf16x8*)&xsb[(w * 16 + lr) * XPAD + ko];
        bf16x8 b0 = *(const bf16x8*)&wsb[( 0 + lr) * XPAD + ko];
        bf16x8 b1 = *(const bf16x8*)&wsb[(16 + lr) * XPAD + ko];
        bf16x8 b2 = *(const bf16x8*)&wsb[(32 + lr) * XPAD + ko];
        bf16x8 b3 = *(const bf16x8*)&wsb[(48 + lr) * XPAD + ko];
        acc0 = __builtin_amdgcn_mfma_f32_16x16x32_bf16(af, b0, acc0, 0, 0, 0);
        acc1 = __builtin_amdgcn_mfma_f32_16x16x32_bf16(af, b1, acc1, 0, 0, 0);
        acc2 = __builtin_amdgcn_mfma_f32_16x16x32_bf16(af, b2, acc2, 0, 0, 0);
        acc3 = __builtin_amdgcn_mfma_f32_16x16x32_bf16(af, b3, acc3, 0, 0, 0);
    }

    #pragma unroll
    for (int j = 0; j < 4; ++j) {
        int node = base + w * 16 + kg * 4 + j;
        if (node < N) {
            float d = dinv[node];
            unsigned short* o = hs1b + (size_t)node * HID + lr;
            o[0]  = bf1(acc0[j] * d);
            o[16] = bf1(acc1[j] * d);
            o[32] = bf1(acc2[j] * d);
            o[48] = bf1(acc3[j] * d);
        }
    }
}

// ================= FUSED: agg1 gather (VALUE-pipelined) + relu/bias + layer-2 GEMM =================
// Node-parallel, 8 lanes/node. Group i+1's hs loads issued BEFORE group i is consumed
// -> 8 VMEM in flight per wave instead of 4.

__launch_bounds__(256)
__global__ void k_fuse2(const uint4* __restrict__ hs, const int* __restrict__ rs,
                        const int* __restrict__ re, const int* __restrict__ csr,
                        const float* __restrict__ dinv,
                        const float* __restrict__ b1, const float* __restrict__ W2,
                        uint2* __restrict__ hs2b, int N) {
    __shared__ float Ws[HID * OUTD];   // 8 KB [k][f]
    __shared__ float L1s[32 * 68];     // 8.7 KB, pad 68
    const int t = threadIdx.x;
    const int base = blockIdx.x * 32;

    for (int i = t; i < HID * OUTD / 4; i += 256)
        ((float4*)Ws)[i] = ((const float4*)W2)[i];

    {   // -------- phase 1: value-pipelined gather --------
        int node = base + (t >> 3);
        int lane = t & 7;
        float fa[8] = {0,0,0,0,0,0,0,0};
        float fb[8] = {0,0,0,0,0,0,0,0};
        float fc[8] = {0,0,0,0,0,0,0,0};
        float fd[8] = {0,0,0,0,0,0,0,0};
        if (node < N) {
            acc8(fa, hs[(size_t)node * 8 + lane]);   // self-loop
            int i = rs[node];
            const int end = re[node];
            const int cnt4 = (end - i) >> 2;
            if (cnt4 > 0) {
                int s0 = __builtin_nontemporal_load(csr + i);
                int s1 = __builtin_nontemporal_load(csr + i + 1);
                int s2 = __builtin_nontemporal_load(csr + i + 2);
                int s3 = __builtin_nontemporal_load(csr + i + 3);
                uint4 q0 = hs[(size_t)s0 * 8 + lane];
                uint4 q1 = hs[(size_t)s1 * 8 + lane];
                uint4 q2 = hs[(size_t)s2 * 8 + lane];
                uint4 q3 = hs[(size_t)s3 * 8 + lane];
                i += 4;
                for (int g = 1; g < cnt4; ++g, i += 4) {
                    int u0 = __builtin_nontemporal_load(csr + i);
                    int u1 = __builtin_nontemporal_load(csr + i + 1);
                    int u2 = __builtin_nontemporal_load(csr + i + 2);
                    int u3 = __builtin_nontemporal_load(csr + i + 3);
                    uint4 p0 = hs[(size_t)u0 * 8 + lane];
                    uint4 p1 = hs[(size_t)u1 * 8 + lane];
                    uint4 p2 = hs[(size_t)u2 * 8 + lane];
                    uint4 p3 = hs[(size_t)u3 * 8 + lane];
                    acc8(fa, q0); acc8(fb, q1); acc8(fc, q2); acc8(fd, q3);
                    q0 = p0; q1 = p1; q2 = p2; q3 = p3;
                }
                acc8(fa, q0); acc8(fb, q1); acc8(fc, q2); acc8(fd, q3);
            }
            for (; i < end; ++i) {
                int s = __builtin_nontemporal_load(csr + i);
                acc8(fa, hs[(size_t)s * 8 + lane]);
            }
            float dn = dinv[node];
            const float4* bb4 = (const float4*)(b1 + lane * 8);
            float4 bv0 = bb4[0], bv1 = bb4[1];
            float* Lrow = &L1s[(t >> 3) * 68 + lane * 8];
            Lrow[0] = fmaxf((fa[0] + fb[0] + fc[0] + fd[0]) * dn + bv0.x, 0.0f);
            Lrow[1] = fmaxf((fa[1] + fb[1] + fc[1] + fd[1]) * dn + bv0.y, 0.0f);
            Lrow[2] = fmaxf((fa[2] + fb[2] + fc[2] + fd[2]) * dn + bv0.z, 0.0f);
            Lrow[3] = fmaxf((fa[3] + fb[3] + fc[3] + fd[3]) * dn + bv0.w, 0.0f);
            Lrow[4] = fmaxf((fa[4] + fb[4] + fc[4] + fd[4]) * dn + bv1.x, 0.0f);
            Lrow[5] = fmaxf((fa[5] + fb[5] + fc[5] + fd[5]) * dn + bv1.y, 0.0f);
            Lrow[6] = fmaxf((fa[6] + fb[6] + fc[6] + fd[6]) * dn + bv1.z, 0.0f);
            Lrow[7] = fmaxf((fa[7] + fb[7] + fc[7] + fd[7]) * dn + bv1.w, 0.0f);
        } else {
            float* Lrow = &L1s[(t >> 3) * 68 + lane * 8];
            #pragma unroll
            for (int j = 0; j < 8; ++j) Lrow[j] = 0.0f;
        }
    }
    __syncthreads();

    {   // -------- phase 2: hs2 = (L1 @ W2) * dinv --------
        const int fq = t & 7;
        const int nl = t >> 3;
        float4 a = {0,0,0,0};
        #pragma unroll 8
        for (int k = 0; k < HID; ++k) {
            float4 w = ((const float4*)Ws)[k * 8 + fq];
            float xv = L1s[nl * 68 + k];
            a.x += xv * w.x; a.y += xv * w.y; a.z += xv * w.z; a.w += xv * w.w;
        }
        int n = base + nl;
        if (n < N) {
            float d = dinv[n];
            a.x *= d; a.y *= d; a.z *= d; a.w *= d;
            hs2b[(size_t)n * 8 + fq] = make_uint2(bfp2(a.x, a.y), bfp2(a.z, a.w));
        }
    }
}

// ================= CSR aggregation, layer 2 (VALUE-pipelined) + fused epilogue =================

__launch_bounds__(256)
__global__ void k_agg2(const uint4* __restrict__ hs, const int* __restrict__ rs,
                       const int* __restrict__ re, const int* __restrict__ csr,
                       const float* __restrict__ dinv,
                       const float* __restrict__ b2, float* __restrict__ out, int N) {
    int tid = blockIdx.x * 256 + threadIdx.x;
    int node = tid >> 2;
    if (node >= N) return;
    int lane = tid & 3;

    float fa[8] = {0,0,0,0,0,0,0,0};
    float fb[8] = {0,0,0,0,0,0,0,0};
    float fc[8] = {0,0,0,0,0,0,0,0};
    float fd[8] = {0,0,0,0,0,0,0,0};
    acc8(fa, hs[(size_t)node * 4 + lane]);   // self-loop
    int i = rs[node];
    const int end = re[node];
    const int cnt4 = (end - i) >> 2;
    if (cnt4 > 0) {
        int s0 = __builtin_nontemporal_load(csr + i);
        int s1 = __builtin_nontemporal_load(csr + i + 1);
        int s2 = __builtin_nontemporal_load(csr + i + 2);
        int s3 = __builtin_nontemporal_load(csr + i + 3);
        uint4 q0 = hs[(size_t)s0 * 4 + lane];
        uint4 q1 = hs[(size_t)s1 * 4 + lane];
        uint4 q2 = hs[(size_t)s2 * 4 + lane];
        uint4 q3 = hs[(size_t)s3 * 4 + lane];
        i += 4;
        for (int g = 1; g < cnt4; ++g, i += 4) {
            int u0 = __builtin_nontemporal_load(csr + i);
            int u1 = __builtin_nontemporal_load(csr + i + 1);
            int u2 = __builtin_nontemporal_load(csr + i + 2);
            int u3 = __builtin_nontemporal_load(csr + i + 3);
            uint4 p0 = hs[(size_t)u0 * 4 + lane];
            uint4 p1 = hs[(size_t)u1 * 4 + lane];
            uint4 p2 = hs[(size_t)u2 * 4 + lane];
            uint4 p3 = hs[(size_t)u3 * 4 + lane];
            acc8(fa, q0); acc8(fb, q1); acc8(fc, q2); acc8(fd, q3);
            q0 = p0; q1 = p1; q2 = p2; q3 = p3;
        }
        acc8(fa, q0); acc8(fb, q1); acc8(fc, q2); acc8(fd, q3);
    }
    for (; i < end; ++i) {
        int s = __builtin_nontemporal_load(csr + i);
        acc8(fa, hs[(size_t)s * 4 + lane]);
    }
    float dn = dinv[node];
    const float4* bb4 = (const float4*)(b2 + lane * 8);
    float4 b0 = bb4[0], b1v = bb4[1];
    float4 o0, o1;
    o0.x = fmaxf((fa[0] + fb[0] + fc[0] + fd[0]) * dn + b0.x, 0.0f);
    o0.y = fmaxf((fa[1] + fb[1] + fc[1] + fd[1]) * dn + b0.y, 0.0f);
    o0.z = fmaxf((fa[2] + fb[2] + fc[2] + fd[2]) * dn + b0.z, 0.0f);
    o0.w = fmaxf((fa[3] + fb[3] + fc[3] + fd[3]) * dn + b0.w, 0.0f);
    o1.x = fmaxf((fa[4] + fb[4] + fc[4] + fd[4]) * dn + b1v.x, 0.0f);
    o1.y = fmaxf((fa[5] + fb[5] + fc[5] + fd[5]) * dn + b1v.y, 0.0f);
    o1.z = fmaxf((fa[6] + fb[6] + fc[6] + fd[6]) * dn + b1v.z, 0.0f);
    o1.w = fmaxf((fa[7] + fb[7] + fc[7] + fd[7]) * dn + b1v.w, 0.0f);
    float4* o = (float4*)(out + (size_t)node * OUTD + lane * 8);
    o[0] = o0;
    o[1] = o1;
}

// ================= launch =================

extern "C" void kernel_launch(void* const* d_in, const int* in_sizes, int n_in,
                              void* d_out, int out_size, void* d_ws, size_t ws_size,
                              hipStream_t stream) {
    const float* x  = (const float*)d_in[0];
    const int*   ei = (const int*)  d_in[1];
    const float* W1 = (const float*)d_in[2];
    const float* b1 = (const float*)d_in[3];
    const float* W2 = (const float*)d_in[4];
    const float* b2 = (const float*)d_in[5];

    const int N = in_sizes[0] / IN_DIM;   // 100000
    const int E = in_sizes[1] / 2;        // 1600000
    const int* srcI = ei;
    const int* dstI = ei + E;
    float* out = (float*)d_out;

    // workspace layout
    float* dinv         = (float*)d_ws;                       // slot 0 (131072)
    int*   rs           = (int*)d_ws + 131072;                // slot 1: N
    int*   re           = (int*)d_ws + 2 * 131072;            // slot 2: N
    int*   bucketCursor = (int*)d_ws + 3 * 131072;            // slot 3: NB
    int*   ebuf         = (int*)d_ws + 4 * 131072;            // NB*BCAP capped buckets
    int*   csr          = ebuf + (size_t)NB * BCAP;           // NB*BCAP capped CSR
    uint2* hs1b         = (uint2*)(csr + (size_t)NB * BCAP);  // bf16 [N][64] (N*16 uint2)
    uint2* hs2b         = hs1b + (size_t)N * 16;              // bf16 [N][32] (N*8 uint2)

    k_binit   <<<1, 256, 0, stream>>>(bucketCursor);
    k_bscatter<<<(E + CHUNK - 1) / CHUNK, 256, 0, stream>>>(srcI, dstI, bucketCursor, ebuf, E);
    k_bfinal  <<<NB, 256, 0, stream>>>(ebuf, bucketCursor, rs, re, dinv, csr, N);

    k_gemm1<<<(N + 63) / 64, 256, 0, stream>>>(x, W1, dinv, (unsigned short*)hs1b, N);
    k_fuse2<<<(N + 31) / 32, 256, 0, stream>>>((const uint4*)hs1b, rs, re, csr, dinv, b1, W2, hs2b, N);
    k_agg2 <<<(N * 4 + 255) / 256, 256, 0, stream>>>((const uint4*)hs2b, rs, re, csr, dinv, b2, out, N);
}